// Round 6
// baseline (469.344 us; speedup 1.0000x reference)
//
#include <hip/hip_runtime.h>

#define N_NEURONS   100000
#define INPUT_SIZE  1024
#define OUTPUT_SIZE 256
#define E_SYN       10000000
#define STEPS       3

#define RANGES      8
#define BIN         12500          // neurons per range; RANGES*BIN == N_NEURONS
#define SCAT_BLK    512
#define CBLK        96             // blocks per range: 768 blocks = 3/CU at 50KB LDS
#define RG          8              // reduce stage-1 groups
#define RSL         (CBLK / RG)    // 12 slabs per group
#define WCH         4096           // edges per wave in reorder
#define NW          2444           // wave slots (611 blocks * 4 waves); NW*WCH >= E
#define B_CNT       611
#define SUBCAPW     656            // per-wave per-range slot cap: 512 + 6.8 sigma, even
#define NPAIR       (NW * SUBCAPW / 2)   // int4 pairs per range (fixed, even)
#define VEC4        (E_SYN / 4)

// v[i] = x[i] for inputs else 0
__global__ void init_state(const float* __restrict__ x, float* __restrict__ v) {
    int i = blockIdx.x * blockDim.x + threadIdx.x;
    if (i < N_NEURONS) v[i] = (i < INPUT_SIZE) ? x[i] : 0.0f;
}

// Single-pass partition. Wave w owns edges [w*WCH, w*WCH+WCH) and, per range r,
// a private slot recs[(r*NW + w)*SUBCAPW .. +SUBCAPW). Cursors in registers
// (uniform across lanes via ballots). Unused slots get neutral records (w=0).
__global__ __launch_bounds__(256) void reorder_slots(
        const float* __restrict__ w,
        const int*   __restrict__ src,
        const int*   __restrict__ dst,
        int2* __restrict__ recs) {
    const int lane  = threadIdx.x & 63;
    const int wslot = blockIdx.x * 4 + (threadIdx.x >> 6);
    const unsigned long long ltmask = (1ull << lane) - 1ull;
    const int* wi = (const int*)w;

    int cur[RANGES] = {0, 0, 0, 0, 0, 0, 0, 0};
    const int ebase = wslot * WCH;

    for (int it = 0; it < WCH / 64; ++it) {
        int  e  = ebase + it * 64 + lane;
        bool ok = (e < E_SYN);
        int  d  = ok ? dst[e] : 0;
        int  sv = ok ? src[e] : 0;
        int  wb = ok ? wi[e]  : 0;
        int  r  = d / BIN;

        unsigned long long okm = __ballot(ok);
        unsigned long long b0  = __ballot(r & 1);
        unsigned long long b1  = __ballot(r & 2);
        unsigned long long b2  = __ballot(r & 4);

        // my range's mask -> rank among same-range lanes
        unsigned long long mym = ((r & 1) ? b0 : ~b0) &
                                 ((r & 2) ? b1 : ~b1) &
                                 ((r & 4) ? b2 : ~b2) & okm;
        int rank = __popcll(mym & ltmask);

        // my base cursor (select chain, uniform values per range)
        int mybase = cur[0];
        mybase = (r == 1) ? cur[1] : mybase;
        mybase = (r == 2) ? cur[2] : mybase;
        mybase = (r == 3) ? cur[3] : mybase;
        mybase = (r == 4) ? cur[4] : mybase;
        mybase = (r == 5) ? cur[5] : mybase;
        mybase = (r == 6) ? cur[6] : mybase;
        mybase = (r == 7) ? cur[7] : mybase;

        int pos = mybase + rank;
        if (ok && pos < SUBCAPW) {
            int2* slab = recs + ((size_t)(r * NW + wslot)) * SUBCAPW;
            slab[pos] = make_int2((sv << 14) | (d - r * BIN), wb);
        }

        // advance all cursors (uniform across lanes)
#pragma unroll
        for (int rr = 0; rr < RANGES; ++rr) {
            unsigned long long m = ((rr & 1) ? b0 : ~b0) &
                                   ((rr & 2) ? b1 : ~b1) &
                                   ((rr & 4) ? b2 : ~b2) & okm;
            int nc = cur[rr] + __popcll(m);
            cur[rr] = (nc > SUBCAPW) ? SUBCAPW : nc;
        }
    }

    // neutral-fill unused slots: w=0, dst spread over bins to avoid pileups
#pragma unroll
    for (int rr = 0; rr < RANGES; ++rr) {
        int2* slab = recs + ((size_t)(rr * NW + wslot)) * SUBCAPW;
        for (int j = cur[rr] + lane; j < SUBCAPW; j += 64)
            slab[j] = make_int2(j & 4095, 0);
    }
}

// Per step: block (r,c) streams a stripe of the fixed-size padded bucket r
// (2 packed edges per int4, unrolled x2 => 4 gathers in flight), LDS-bins,
// flushes private partial slab. No device atomics, no counts needed.
__global__ __launch_bounds__(SCAT_BLK) void scatter_sorted(
        const int2* __restrict__ recs,
        const float* __restrict__ v,
        float* __restrict__ partials) {
    __shared__ float bins[BIN];
    const int r = blockIdx.x / CBLK;
    const int c = blockIdx.x % CBLK;
    for (int j = threadIdx.x; j < BIN; j += SCAT_BLK) bins[j] = 0.0f;
    __syncthreads();

    const int4* base4 = (const int4*)(recs + (size_t)r * NW * SUBCAPW);
    const int stride = CBLK * SCAT_BLK;
    int u = c * SCAT_BLK + threadIdx.x;
    for (; u + stride < NPAIR; u += 2 * stride) {
        int4 a = base4[u];
        int4 b = base4[u + stride];
        float va0 = v[a.x >> 14];
        float va1 = v[a.z >> 14];
        float vb0 = v[b.x >> 14];
        float vb1 = v[b.z >> 14];
        atomicAdd(&bins[a.x & 16383], va0 * __int_as_float(a.y));
        atomicAdd(&bins[a.z & 16383], va1 * __int_as_float(a.w));
        atomicAdd(&bins[b.x & 16383], vb0 * __int_as_float(b.y));
        atomicAdd(&bins[b.z & 16383], vb1 * __int_as_float(b.w));
    }
    if (u < NPAIR) {
        int4 a = base4[u];
        atomicAdd(&bins[a.x & 16383], v[a.x >> 14] * __int_as_float(a.y));
        atomicAdd(&bins[a.z & 16383], v[a.z >> 14] * __int_as_float(a.w));
    }
    __syncthreads();
    float* o = partials + (size_t)(r * CBLK + c) * BIN;
    for (int j = threadIdx.x; j < BIN; j += SCAT_BLK) o[j] = bins[j];
}

// Reduce stage 1: group g sums RSL slabs -> p2[g][N].
__global__ void reduce_stage1(const float* __restrict__ partials,
                              float* __restrict__ p2) {
    int i4 = 4 * (blockIdx.x * blockDim.x + threadIdx.x);
    if (i4 >= N_NEURONS) return;
    const int g = blockIdx.y;
    const int r = i4 / BIN;
    const int j = i4 - r * BIN;
    const float* base = partials + ((size_t)(r * CBLK + g * RSL)) * BIN + j;
    float4 acc = {0.f, 0.f, 0.f, 0.f};
#pragma unroll
    for (int c = 0; c < RSL; ++c) {
        float4 p = *(const float4*)(base + (size_t)c * BIN);
        acc.x += p.x; acc.y += p.y; acc.z += p.z; acc.w += p.w;
    }
    *(float4*)(p2 + (size_t)g * N_NEURONS + i4) = acc;
}

// Reduce stage 2: sum RG group-partials, add bias, tanh (except outputs).
__global__ void reduce_stage2(const float* __restrict__ p2,
                              const float* __restrict__ bias,
                              float* __restrict__ v,
                              float* __restrict__ out,
                              int write_out) {
    int i4 = 4 * (blockIdx.x * blockDim.x + threadIdx.x);
    if (i4 >= N_NEURONS) return;
    float4 acc = {0.f, 0.f, 0.f, 0.f};
#pragma unroll
    for (int g = 0; g < RG; ++g) {
        float4 p = *(const float4*)(p2 + (size_t)g * N_NEURONS + i4);
        acc.x += p.x; acc.y += p.y; acc.z += p.z; acc.w += p.w;
    }
    float av[4] = {acc.x, acc.y, acc.z, acc.w};
#pragma unroll
    for (int k = 0; k < 4; ++k) {
        int i = i4 + k;
        float val = av[k] + ((i >= INPUT_SIZE) ? bias[i - INPUT_SIZE] : 0.0f);
        float nv  = (i < N_NEURONS - OUTPUT_SIZE) ? tanhf(val) : val;
        v[i] = nv;
        if (write_out && i >= N_NEURONS - OUTPUT_SIZE)
            out[i - (N_NEURONS - OUTPUT_SIZE)] = val;
    }
}

// ---- fallback (small ws): multi-pass binned rescan path ----
__global__ void scatter_binned(const float* __restrict__ w,
                               const int*   __restrict__ src,
                               const int*   __restrict__ dst,
                               const float* __restrict__ v,
                               float*       __restrict__ partials,
                               int C) {
    __shared__ float bins[BIN];
    const int r = blockIdx.x / C;
    const int c = blockIdx.x % C;
    const int lo = r * BIN;
    const int hi = lo + BIN;
    for (int j = threadIdx.x; j < BIN; j += blockDim.x) bins[j] = 0.0f;
    __syncthreads();
    const int4*   src4 = (const int4*)src;
    const int4*   dst4 = (const int4*)dst;
    const float4* w4v  = (const float4*)w;
    const int stride = C * blockDim.x;
    for (int u = c * blockDim.x + threadIdx.x; u < VEC4; u += stride) {
        const int4   s4 = src4[u];
        const int4   d4 = dst4[u];
        const float4 wv = w4v[u];
        int   s[4] = {s4.x, s4.y, s4.z, s4.w};
        int   d[4] = {d4.x, d4.y, d4.z, d4.w};
        float ww[4] = {wv.x, wv.y, wv.z, wv.w};
#pragma unroll
        for (int k = 0; k < 4; ++k)
            if (d[k] >= lo && d[k] < hi)
                atomicAdd(&bins[d[k] - lo], v[s[k]] * ww[k]);
    }
    __syncthreads();
    float* o = partials + ((size_t)(r * C + c)) * BIN;
    for (int j = threadIdx.x; j < BIN; j += blockDim.x) o[j] = bins[j];
}
__global__ void reduce_update_fb(const float* __restrict__ partials,
                                 const float* __restrict__ bias,
                                 float* __restrict__ v,
                                 float* __restrict__ out,
                                 int C, int write_out) {
    int i4 = 4 * (blockIdx.x * blockDim.x + threadIdx.x);
    if (i4 >= N_NEURONS) return;
    const int r = i4 / BIN;
    const int j = i4 - r * BIN;
    const float* base = partials + ((size_t)r * C) * BIN + j;
    float4 acc = {0.f, 0.f, 0.f, 0.f};
    for (int c = 0; c < C; ++c) {
        float4 p = *(const float4*)(base + (size_t)c * BIN);
        acc.x += p.x; acc.y += p.y; acc.z += p.z; acc.w += p.w;
    }
    float av[4] = {acc.x, acc.y, acc.z, acc.w};
#pragma unroll
    for (int k = 0; k < 4; ++k) {
        int i = i4 + k;
        float val = av[k] + ((i >= INPUT_SIZE) ? bias[i - INPUT_SIZE] : 0.0f);
        float nv  = (i < N_NEURONS - OUTPUT_SIZE) ? tanhf(val) : val;
        v[i] = nv;
        if (write_out && i >= N_NEURONS - OUTPUT_SIZE)
            out[i - (N_NEURONS - OUTPUT_SIZE)] = val;
    }
}

extern "C" void kernel_launch(void* const* d_in, const int* in_sizes, int n_in,
                              void* d_out, int out_size, void* d_ws, size_t ws_size,
                              hipStream_t stream) {
    const float* x    = (const float*)d_in[0];
    const float* w    = (const float*)d_in[1];
    const float* bias = (const float*)d_in[2];
    const int*   src  = (const int*)d_in[3];
    const int*   dst  = (const int*)d_in[4];
    float* out = (float*)d_out;

    const int blk = 256;
    const int grid_n   = (N_NEURONS + blk - 1) / blk;
    const int red_grid = (N_NEURONS / 4 + blk - 1) / blk;

    // sorted-path ws layout: v | partials | p2 | recs
    float* v        = (float*)d_ws;
    float* partials = v + N_NEURONS;
    float* p2       = partials + (size_t)RANGES * CBLK * BIN;
    int2*  recs     = (int2*)(p2 + (size_t)RG * N_NEURONS);
    size_t need = (size_t)((char*)(recs + (size_t)RANGES * NW * SUBCAPW) - (char*)d_ws);

    if (ws_size >= need) {
        init_state<<<grid_n, blk, 0, stream>>>(x, v);
        reorder_slots<<<B_CNT, 256, 0, stream>>>(w, src, dst, recs);
        for (int s = 0; s < STEPS; ++s) {
            scatter_sorted<<<RANGES * CBLK, SCAT_BLK, 0, stream>>>(recs, v, partials);
            reduce_stage1<<<dim3(red_grid, RG), blk, 0, stream>>>(partials, p2);
            reduce_stage2<<<red_grid, blk, 0, stream>>>(
                p2, bias, v, out, s == STEPS - 1 ? 1 : 0);
        }
    } else {
        long C = (long)(ws_size / 4 / N_NEURONS) - 1;
        if (C > 64) C = 64;
        if (C < 1) C = 1;
        float* part_fb = v + N_NEURONS;
        init_state<<<grid_n, blk, 0, stream>>>(x, v);
        for (int s = 0; s < STEPS; ++s) {
            scatter_binned<<<RANGES * (int)C, SCAT_BLK, 0, stream>>>(
                w, src, dst, v, part_fb, (int)C);
            reduce_update_fb<<<red_grid, blk, 0, stream>>>(
                part_fb, bias, v, out, (int)C, s == STEPS - 1 ? 1 : 0);
        }
    }
}

// Round 7
// 421.377 us; speedup vs baseline: 1.1138x; 1.1138x over previous
//
#include <hip/hip_runtime.h>

#define N_NEURONS   100000
#define INPUT_SIZE  1024
#define OUTPUT_SIZE 256
#define E_SYN       10000000
#define STEPS       3

#define RANGES      8
#define BIN         12500          // neurons per range; RANGES*BIN == N_NEURONS
#define SCAT_BLK    512
#define CBLK        96             // blocks per range: 768 blocks = 3/CU at 50KB LDS
#define RG          8              // reduce stage-1 groups
#define RSL         (CBLK / RG)    // 12 slabs per group
#define CAP         1280000        // per-range bucket capacity (mean 1.25M, ~28 sigma)
#define RB_BLK      256            // reorder block size
#define CH          4000           // edges per reorder block
#define B_CNT       2500           // 2500 * 4000 == E_SYN
#define VEC4        (E_SYN / 4)

// v init + zero the 8 global range cursors
__global__ void init_all(const float* __restrict__ x, float* __restrict__ v,
                         int* __restrict__ gcur) {
    int i = blockIdx.x * blockDim.x + threadIdx.x;
    if (i < N_NEURONS) v[i] = (i < INPUT_SIZE) ? x[i] : 0.0f;
    if (i < RANGES) gcur[i] = 0;
}

// One-time partition into range-major buckets of packed 8B records
// code = (src << 14) | dst_local. Bit-sliced ballot ranking (R5 structure:
// best measured occupancy/VALU tradeoff).
__global__ __launch_bounds__(RB_BLK) void reorder_partition(
        const float* __restrict__ w,
        const int*   __restrict__ src,
        const int*   __restrict__ dst,
        int2* __restrict__ recs,
        int*  __restrict__ gcur) {
    __shared__ int cnt[RANGES];
    __shared__ int cursor[RANGES];
    __shared__ int wbase[RB_BLK / 64][RANGES];
    const int tid  = threadIdx.x;
    const int lane = tid & 63;
    const int wv   = tid >> 6;
    const unsigned long long ltmask = (1ull << lane) - 1ull;
    if (tid < RANGES) cnt[tid] = 0;
    __syncthreads();

    const int beg  = blockIdx.x * CH;
    const int endx = beg + CH;
    const int ITER = (CH + RB_BLK - 1) / RB_BLK;
    const int* wi  = (const int*)w;

    // phase 1: wave histogram, fully scalar after 4 ballots
    int h[RANGES] = {0, 0, 0, 0, 0, 0, 0, 0};
    for (int it = 0; it < ITER; ++it) {
        int  e  = beg + it * RB_BLK + tid;
        bool ok = (e < endx);
        int  d  = ok ? dst[e] : 0;
        int  r  = d / BIN;
        unsigned long long okm = __ballot(ok);
        unsigned long long b0  = __ballot(r & 1);
        unsigned long long b1  = __ballot(r & 2);
        unsigned long long b2  = __ballot(r & 4);
#pragma unroll
        for (int rr = 0; rr < RANGES; ++rr) {
            unsigned long long m = ((rr & 1) ? b0 : ~b0) &
                                   ((rr & 2) ? b1 : ~b1) &
                                   ((rr & 4) ? b2 : ~b2) & okm;
            h[rr] += __popcll(m);
        }
    }
    if (lane < RANGES) {
        int t = h[0];
#pragma unroll
        for (int rr = 1; rr < RANGES; ++rr) if (lane == rr) t = h[rr];
        atomicAdd(&cnt[lane], t);
    }
    __syncthreads();
    if (tid < RANGES) cursor[tid] = tid * CAP + atomicAdd(&gcur[tid], cnt[tid]);
    __syncthreads();

    // phase 2: rank + write. One LDS atomic per wave-iter, base via LDS.
    for (int it = 0; it < ITER; ++it) {
        int  e  = beg + it * RB_BLK + tid;
        bool ok = (e < endx);
        int  d  = ok ? dst[e] : 0;
        int  sv = ok ? src[e] : 0;
        int  wb = ok ? wi[e]  : 0;
        int  r  = d / BIN;
        unsigned long long okm = __ballot(ok);
        unsigned long long b0  = __ballot(r & 1);
        unsigned long long b1  = __ballot(r & 2);
        unsigned long long b2  = __ballot(r & 4);
        unsigned long long s0 = (lane & 1) ? b0 : ~b0;
        unsigned long long s1 = (lane & 2) ? b1 : ~b1;
        unsigned long long s2 = (lane & 4) ? b2 : ~b2;
        int tot = __popcll(s0 & s1 & s2 & okm);
        if (lane < RANGES) wbase[wv][lane] = atomicAdd(&cursor[lane], tot);
        unsigned long long m0 = (r & 1) ? b0 : ~b0;
        unsigned long long m1 = (r & 2) ? b1 : ~b1;
        unsigned long long m2 = (r & 4) ? b2 : ~b2;
        unsigned long long mym = m0 & m1 & m2 & okm;
        int base = wbase[wv][r];   // same-wave DS ordering guarantees visibility
        int pos  = base + __popcll(mym & ltmask);
        if (ok) recs[pos] = make_int2((sv << 14) | (d - r * BIN), wb);
    }
}

// Per step: block (r,c) streams a stripe of bucket r (2 packed edges per int4,
// 4x unrolled => 8 independent gathers in flight), LDS-bins, flushes slab.
__global__ __launch_bounds__(SCAT_BLK) void scatter_sorted(
        const int2* __restrict__ recs,
        const int*  __restrict__ gcur,
        const float* __restrict__ v,
        float* __restrict__ partials) {
    __shared__ float bins[BIN];
    const int r = blockIdx.x / CBLK;
    const int c = blockIdx.x % CBLK;
    for (int j = threadIdx.x; j < BIN; j += SCAT_BLK) bins[j] = 0.0f;
    __syncthreads();

    const int cnt   = gcur[r];
    const int npair = cnt >> 1;
    const int4* base4 = (const int4*)(recs + (size_t)r * CAP);
    const int stride = CBLK * SCAT_BLK;
    int u = c * SCAT_BLK + threadIdx.x;
    for (; u + 3 * stride < npair; u += 4 * stride) {
        int4 a = base4[u];
        int4 b = base4[u + stride];
        int4 e = base4[u + 2 * stride];
        int4 f = base4[u + 3 * stride];
        float va0 = v[a.x >> 14];
        float va1 = v[a.z >> 14];
        float vb0 = v[b.x >> 14];
        float vb1 = v[b.z >> 14];
        float ve0 = v[e.x >> 14];
        float ve1 = v[e.z >> 14];
        float vf0 = v[f.x >> 14];
        float vf1 = v[f.z >> 14];
        atomicAdd(&bins[a.x & 16383], va0 * __int_as_float(a.y));
        atomicAdd(&bins[a.z & 16383], va1 * __int_as_float(a.w));
        atomicAdd(&bins[b.x & 16383], vb0 * __int_as_float(b.y));
        atomicAdd(&bins[b.z & 16383], vb1 * __int_as_float(b.w));
        atomicAdd(&bins[e.x & 16383], ve0 * __int_as_float(e.y));
        atomicAdd(&bins[e.z & 16383], ve1 * __int_as_float(e.w));
        atomicAdd(&bins[f.x & 16383], vf0 * __int_as_float(f.y));
        atomicAdd(&bins[f.z & 16383], vf1 * __int_as_float(f.w));
    }
    for (; u < npair; u += stride) {
        int4 a = base4[u];
        atomicAdd(&bins[a.x & 16383], v[a.x >> 14] * __int_as_float(a.y));
        atomicAdd(&bins[a.z & 16383], v[a.z >> 14] * __int_as_float(a.w));
    }
    if ((cnt & 1) && c == 0 && threadIdx.x == 0) {
        int2 p = recs[(size_t)r * CAP + cnt - 1];
        atomicAdd(&bins[p.x & 16383], v[p.x >> 14] * __int_as_float(p.y));
    }
    __syncthreads();
    float* o = partials + (size_t)(r * CBLK + c) * BIN;
    for (int j = threadIdx.x; j < BIN; j += SCAT_BLK) o[j] = bins[j];
}

// Reduce stage 1: group g sums RSL slabs -> p2[g][N].
__global__ void reduce_stage1(const float* __restrict__ partials,
                              float* __restrict__ p2) {
    int i4 = 4 * (blockIdx.x * blockDim.x + threadIdx.x);
    if (i4 >= N_NEURONS) return;
    const int g = blockIdx.y;
    const int r = i4 / BIN;
    const int j = i4 - r * BIN;
    const float* base = partials + ((size_t)(r * CBLK + g * RSL)) * BIN + j;
    float4 acc = {0.f, 0.f, 0.f, 0.f};
#pragma unroll
    for (int c = 0; c < RSL; ++c) {
        float4 p = *(const float4*)(base + (size_t)c * BIN);
        acc.x += p.x; acc.y += p.y; acc.z += p.z; acc.w += p.w;
    }
    *(float4*)(p2 + (size_t)g * N_NEURONS + i4) = acc;
}

// Reduce stage 2: sum RG group-partials, add bias, tanh (except outputs).
__global__ void reduce_stage2(const float* __restrict__ p2,
                              const float* __restrict__ bias,
                              float* __restrict__ v,
                              float* __restrict__ out,
                              int write_out) {
    int i4 = 4 * (blockIdx.x * blockDim.x + threadIdx.x);
    if (i4 >= N_NEURONS) return;
    float4 acc = {0.f, 0.f, 0.f, 0.f};
#pragma unroll
    for (int g = 0; g < RG; ++g) {
        float4 p = *(const float4*)(p2 + (size_t)g * N_NEURONS + i4);
        acc.x += p.x; acc.y += p.y; acc.z += p.z; acc.w += p.w;
    }
    float av[4] = {acc.x, acc.y, acc.z, acc.w};
#pragma unroll
    for (int k = 0; k < 4; ++k) {
        int i = i4 + k;
        float val = av[k] + ((i >= INPUT_SIZE) ? bias[i - INPUT_SIZE] : 0.0f);
        float nv  = (i < N_NEURONS - OUTPUT_SIZE) ? tanhf(val) : val;
        v[i] = nv;
        if (write_out && i >= N_NEURONS - OUTPUT_SIZE)
            out[i - (N_NEURONS - OUTPUT_SIZE)] = val;
    }
}

// ---- fallback (small ws): multi-pass binned rescan path ----
__global__ void init_state_fb(const float* __restrict__ x, float* __restrict__ v) {
    int i = blockIdx.x * blockDim.x + threadIdx.x;
    if (i < N_NEURONS) v[i] = (i < INPUT_SIZE) ? x[i] : 0.0f;
}
__global__ void scatter_binned(const float* __restrict__ w,
                               const int*   __restrict__ src,
                               const int*   __restrict__ dst,
                               const float* __restrict__ v,
                               float*       __restrict__ partials,
                               int C) {
    __shared__ float bins[BIN];
    const int r = blockIdx.x / C;
    const int c = blockIdx.x % C;
    const int lo = r * BIN;
    const int hi = lo + BIN;
    for (int j = threadIdx.x; j < BIN; j += blockDim.x) bins[j] = 0.0f;
    __syncthreads();
    const int4*   src4 = (const int4*)src;
    const int4*   dst4 = (const int4*)dst;
    const float4* w4v  = (const float4*)w;
    const int stride = C * blockDim.x;
    for (int u = c * blockDim.x + threadIdx.x; u < VEC4; u += stride) {
        const int4   s4 = src4[u];
        const int4   d4 = dst4[u];
        const float4 wv = w4v[u];
        int   s[4] = {s4.x, s4.y, s4.z, s4.w};
        int   d[4] = {d4.x, d4.y, d4.z, d4.w};
        float ww[4] = {wv.x, wv.y, wv.z, wv.w};
#pragma unroll
        for (int k = 0; k < 4; ++k)
            if (d[k] >= lo && d[k] < hi)
                atomicAdd(&bins[d[k] - lo], v[s[k]] * ww[k]);
    }
    __syncthreads();
    float* o = partials + ((size_t)(r * C + c)) * BIN;
    for (int j = threadIdx.x; j < BIN; j += blockDim.x) o[j] = bins[j];
}
__global__ void reduce_update_fb(const float* __restrict__ partials,
                                 const float* __restrict__ bias,
                                 float* __restrict__ v,
                                 float* __restrict__ out,
                                 int C, int write_out) {
    int i4 = 4 * (blockIdx.x * blockDim.x + threadIdx.x);
    if (i4 >= N_NEURONS) return;
    const int r = i4 / BIN;
    const int j = i4 - r * BIN;
    const float* base = partials + ((size_t)r * C) * BIN + j;
    float4 acc = {0.f, 0.f, 0.f, 0.f};
    for (int c = 0; c < C; ++c) {
        float4 p = *(const float4*)(base + (size_t)c * BIN);
        acc.x += p.x; acc.y += p.y; acc.z += p.z; acc.w += p.w;
    }
    float av[4] = {acc.x, acc.y, acc.z, acc.w};
#pragma unroll
    for (int k = 0; k < 4; ++k) {
        int i = i4 + k;
        float val = av[k] + ((i >= INPUT_SIZE) ? bias[i - INPUT_SIZE] : 0.0f);
        float nv  = (i < N_NEURONS - OUTPUT_SIZE) ? tanhf(val) : val;
        v[i] = nv;
        if (write_out && i >= N_NEURONS - OUTPUT_SIZE)
            out[i - (N_NEURONS - OUTPUT_SIZE)] = val;
    }
}

extern "C" void kernel_launch(void* const* d_in, const int* in_sizes, int n_in,
                              void* d_out, int out_size, void* d_ws, size_t ws_size,
                              hipStream_t stream) {
    const float* x    = (const float*)d_in[0];
    const float* w    = (const float*)d_in[1];
    const float* bias = (const float*)d_in[2];
    const int*   src  = (const int*)d_in[3];
    const int*   dst  = (const int*)d_in[4];
    float* out = (float*)d_out;

    const int blk = 256;
    const int grid_n   = (N_NEURONS + blk - 1) / blk;
    const int red_grid = (N_NEURONS / 4 + blk - 1) / blk;

    // sorted-path ws layout: v | partials | p2 | recs | gcur
    float* v        = (float*)d_ws;
    float* partials = v + N_NEURONS;
    float* p2       = partials + (size_t)RANGES * CBLK * BIN;
    int2*  recs     = (int2*)(p2 + (size_t)RG * N_NEURONS);
    int*   gcur     = (int*)(recs + (size_t)RANGES * CAP);
    size_t need = (size_t)((char*)(gcur + RANGES) - (char*)d_ws);

    if (ws_size >= need) {
        init_all<<<grid_n, blk, 0, stream>>>(x, v, gcur);
        reorder_partition<<<B_CNT, RB_BLK, 0, stream>>>(w, src, dst, recs, gcur);
        for (int s = 0; s < STEPS; ++s) {
            scatter_sorted<<<RANGES * CBLK, SCAT_BLK, 0, stream>>>(
                recs, gcur, v, partials);
            reduce_stage1<<<dim3(red_grid, RG), blk, 0, stream>>>(partials, p2);
            reduce_stage2<<<red_grid, blk, 0, stream>>>(
                p2, bias, v, out, s == STEPS - 1 ? 1 : 0);
        }
    } else {
        long C = (long)(ws_size / 4 / N_NEURONS) - 1;
        if (C > 64) C = 64;
        if (C < 1) C = 1;
        float* part_fb = v + N_NEURONS;
        init_state_fb<<<grid_n, blk, 0, stream>>>(x, v);
        for (int s = 0; s < STEPS; ++s) {
            scatter_binned<<<RANGES * (int)C, SCAT_BLK, 0, stream>>>(
                w, src, dst, v, part_fb, (int)C);
            reduce_update_fb<<<red_grid, blk, 0, stream>>>(
                part_fb, bias, v, out, (int)C, s == STEPS - 1 ? 1 : 0);
        }
    }
}

// Round 8
// 398.420 us; speedup vs baseline: 1.1780x; 1.0576x over previous
//
#include <hip/hip_runtime.h>

#define N_NEURONS   100000
#define INPUT_SIZE  1024
#define OUTPUT_SIZE 256
#define E_SYN       10000000
#define STEPS       3

#define RANGES      8
#define BIN         12500          // neurons per range; RANGES*BIN == N_NEURONS
#define SCAT_BLK    1024           // 2 blocks/CU -> 32 waves/CU (100% occupancy)
#define CBLK        64             // blocks per range in scatter
#define RG          8              // reduce stage-1 groups
#define RSL         (CBLK / RG)    // 8 slabs per group
#define CAP         1280000        // per-range bucket capacity (mean 1.25M, ~28 sigma)
#define RB_BLK      256            // reorder block size (4 waves)
#define RB_WAVES    4
#define CH          8192           // edges per reorder block
#define B_CNT       1221           // ceil(E / CH)
#define STG_CAP     128            // staging ring entries per range per wave
#define VEC4        (E_SYN / 4)

// v init + zero the 8 global range cursors
__global__ void init_all(const float* __restrict__ x, float* __restrict__ v,
                         int* __restrict__ gcur) {
    int i = blockIdx.x * blockDim.x + threadIdx.x;
    if (i < N_NEURONS) v[i] = (i < INPUT_SIZE) ? x[i] : 0.0f;
    if (i < RANGES) gcur[i] = 0;
}

// One-time partition into range-major buckets of packed 8B records
// code = (src << 14) | dst_local. v3: int4 streams + LDS staging rings so all
// global record writes are dense 512B coalesced bursts (no divergent stores).
__global__ __launch_bounds__(RB_BLK) void reorder_partition(
        const float* __restrict__ w,
        const int*   __restrict__ src,
        const int*   __restrict__ dst,
        int2* __restrict__ recs,
        int*  __restrict__ gcur) {
    __shared__ int cnt[RANGES];
    __shared__ int blk_cur[RANGES];
    __shared__ int2 stg[RB_WAVES][RANGES][STG_CAP];
    const int tid  = threadIdx.x;
    const int lane = tid & 63;
    const int wv   = tid >> 6;
    const unsigned long long ltmask = (1ull << lane) - 1ull;
    if (tid < RANGES) cnt[tid] = 0;
    __syncthreads();

    const long beg = (long)blockIdx.x * CH;
    const int4* dst4 = (const int4*)dst;
    const int4* src4 = (const int4*)src;
    const int4* wq4  = (const int4*)w;
    const int ITER = CH / (RB_BLK * 4);   // 8

    // ---- phase 1: per-block histogram (dst only, int4 loads) ----
    {
        int h[RANGES] = {0, 0, 0, 0, 0, 0, 0, 0};
        for (int it = 0; it < ITER; ++it) {
            long e  = beg + (long)it * RB_BLK * 4 + (long)tid * 4;
            bool ok = (e < E_SYN);
            int4 d4 = ok ? dst4[e >> 2] : make_int4(0, 0, 0, 0);
            unsigned long long okm = __ballot(ok);
            int rk[4] = {d4.x / BIN, d4.y / BIN, d4.z / BIN, d4.w / BIN};
#pragma unroll
            for (int k = 0; k < 4; ++k) {
                unsigned long long b0 = __ballot(rk[k] & 1);
                unsigned long long b1 = __ballot(rk[k] & 2);
                unsigned long long b2 = __ballot(rk[k] & 4);
#pragma unroll
                for (int rr = 0; rr < RANGES; ++rr) {
                    unsigned long long m = ((rr & 1) ? b0 : ~b0) &
                                           ((rr & 2) ? b1 : ~b1) &
                                           ((rr & 4) ? b2 : ~b2) & okm;
                    h[rr] += __popcll(m);
                }
            }
        }
        if (lane < RANGES) {
            int t = h[0];
#pragma unroll
            for (int rr = 1; rr < RANGES; ++rr) if (lane == rr) t = h[rr];
            atomicAdd(&cnt[lane], t);
        }
    }
    __syncthreads();
    if (tid < RANGES) blk_cur[tid] = tid * CAP + atomicAdd(&gcur[tid], cnt[tid]);
    __syncthreads();

    // ---- phase 2: rank into LDS staging rings, flush dense 64-record bursts ----
    int wr[RANGES] = {0, 0, 0, 0, 0, 0, 0, 0};
    int fl[RANGES] = {0, 0, 0, 0, 0, 0, 0, 0};
    for (int it = 0; it < ITER; ++it) {
        long e  = beg + (long)it * RB_BLK * 4 + (long)tid * 4;
        bool ok = (e < E_SYN);
        int4 d4 = ok ? dst4[e >> 2] : make_int4(0, 0, 0, 0);
        int4 s4 = ok ? src4[e >> 2] : make_int4(0, 0, 0, 0);
        int4 q4 = ok ? wq4[e >> 2]  : make_int4(0, 0, 0, 0);
        unsigned long long okm = __ballot(ok);
        int dd[4] = {d4.x, d4.y, d4.z, d4.w};
        int ss[4] = {s4.x, s4.y, s4.z, s4.w};
        int qq[4] = {q4.x, q4.y, q4.z, q4.w};
#pragma unroll
        for (int k = 0; k < 4; ++k) {
            int r = dd[k] / BIN;
            unsigned long long b0 = __ballot(r & 1);
            unsigned long long b1 = __ballot(r & 2);
            unsigned long long b2 = __ballot(r & 4);
            unsigned long long mym = ((r & 1) ? b0 : ~b0) &
                                     ((r & 2) ? b1 : ~b1) &
                                     ((r & 4) ? b2 : ~b2) & okm;
            int rank = __popcll(mym & ltmask);
            // my range's ring cursor (values uniform across lanes)
            int base = wr[0];
            base = (r == 1) ? wr[1] : base;
            base = (r == 2) ? wr[2] : base;
            base = (r == 3) ? wr[3] : base;
            base = (r == 4) ? wr[4] : base;
            base = (r == 5) ? wr[5] : base;
            base = (r == 6) ? wr[6] : base;
            base = (r == 7) ? wr[7] : base;
            int slot = (base + rank) & (STG_CAP - 1);
            if (ok) stg[wv][r][slot] = make_int2((ss[k] << 14) | (dd[k] - r * BIN), qq[k]);
            // advance all ring cursors (uniform)
#pragma unroll
            for (int rr = 0; rr < RANGES; ++rr) {
                unsigned long long m = ((rr & 1) ? b0 : ~b0) &
                                       ((rr & 2) ? b1 : ~b1) &
                                       ((rr & 4) ? b2 : ~b2) & okm;
                wr[rr] += __popcll(m);
            }
            // flush full 64-record bursts (wave-uniform branches)
#pragma unroll
            for (int rr = 0; rr < RANGES; ++rr) {
                if (wr[rr] - fl[rr] >= 64) {
                    int gpos = 0;
                    if (lane == 0) gpos = atomicAdd(&blk_cur[rr], 64);
                    gpos = __shfl(gpos, 0, 64);
                    int2 rec = stg[wv][rr][(fl[rr] & (STG_CAP - 1)) + lane];
                    recs[(size_t)gpos + lane] = rec;
                    fl[rr] += 64;
                }
            }
        }
    }
    // drain remainders (<64 each, no ring wrap since fl is 64-aligned)
#pragma unroll
    for (int rr = 0; rr < RANGES; ++rr) {
        int pend = wr[rr] - fl[rr];
        if (pend > 0) {
            int gpos = 0;
            if (lane == 0) gpos = atomicAdd(&blk_cur[rr], pend);
            gpos = __shfl(gpos, 0, 64);
            if (lane < pend) {
                int2 rec = stg[wv][rr][(fl[rr] & (STG_CAP - 1)) + lane];
                recs[(size_t)gpos + lane] = rec;
            }
        }
    }
}

// Per step: block (r,c) streams a stripe of bucket r (2 packed edges per int4,
// 4x unrolled), LDS-bins, flushes partial slab. 1024 thr -> 32 waves/CU.
__global__ __launch_bounds__(SCAT_BLK) void scatter_sorted(
        const int2* __restrict__ recs,
        const int*  __restrict__ gcur,
        const float* __restrict__ v,
        float* __restrict__ partials) {
    __shared__ float bins[BIN];
    const int r = blockIdx.x / CBLK;
    const int c = blockIdx.x % CBLK;
    for (int j = threadIdx.x; j < BIN; j += SCAT_BLK) bins[j] = 0.0f;
    __syncthreads();

    const int cnt   = gcur[r];
    const int npair = cnt >> 1;
    const int4* base4 = (const int4*)(recs + (size_t)r * CAP);
    const int stride = CBLK * SCAT_BLK;
    int u = c * SCAT_BLK + threadIdx.x;
    for (; u + 3 * stride < npair; u += 4 * stride) {
        int4 a = base4[u];
        int4 b = base4[u + stride];
        int4 e = base4[u + 2 * stride];
        int4 f = base4[u + 3 * stride];
        float va0 = v[a.x >> 14];
        float va1 = v[a.z >> 14];
        float vb0 = v[b.x >> 14];
        float vb1 = v[b.z >> 14];
        float ve0 = v[e.x >> 14];
        float ve1 = v[e.z >> 14];
        float vf0 = v[f.x >> 14];
        float vf1 = v[f.z >> 14];
        atomicAdd(&bins[a.x & 16383], va0 * __int_as_float(a.y));
        atomicAdd(&bins[a.z & 16383], va1 * __int_as_float(a.w));
        atomicAdd(&bins[b.x & 16383], vb0 * __int_as_float(b.y));
        atomicAdd(&bins[b.z & 16383], vb1 * __int_as_float(b.w));
        atomicAdd(&bins[e.x & 16383], ve0 * __int_as_float(e.y));
        atomicAdd(&bins[e.z & 16383], ve1 * __int_as_float(e.w));
        atomicAdd(&bins[f.x & 16383], vf0 * __int_as_float(f.y));
        atomicAdd(&bins[f.z & 16383], vf1 * __int_as_float(f.w));
    }
    for (; u < npair; u += stride) {
        int4 a = base4[u];
        atomicAdd(&bins[a.x & 16383], v[a.x >> 14] * __int_as_float(a.y));
        atomicAdd(&bins[a.z & 16383], v[a.z >> 14] * __int_as_float(a.w));
    }
    if ((cnt & 1) && c == 0 && threadIdx.x == 0) {
        int2 p = recs[(size_t)r * CAP + cnt - 1];
        atomicAdd(&bins[p.x & 16383], v[p.x >> 14] * __int_as_float(p.y));
    }
    __syncthreads();
    float* o = partials + (size_t)(r * CBLK + c) * BIN;
    for (int j = threadIdx.x; j < BIN; j += SCAT_BLK) o[j] = bins[j];
}

// Reduce stage 1: group g sums RSL slabs -> p2[g][N].
__global__ void reduce_stage1(const float* __restrict__ partials,
                              float* __restrict__ p2) {
    int i4 = 4 * (blockIdx.x * blockDim.x + threadIdx.x);
    if (i4 >= N_NEURONS) return;
    const int g = blockIdx.y;
    const int r = i4 / BIN;
    const int j = i4 - r * BIN;
    const float* base = partials + ((size_t)(r * CBLK + g * RSL)) * BIN + j;
    float4 acc = {0.f, 0.f, 0.f, 0.f};
#pragma unroll
    for (int c = 0; c < RSL; ++c) {
        float4 p = *(const float4*)(base + (size_t)c * BIN);
        acc.x += p.x; acc.y += p.y; acc.z += p.z; acc.w += p.w;
    }
    *(float4*)(p2 + (size_t)g * N_NEURONS + i4) = acc;
}

// Reduce stage 2: sum RG group-partials, add bias, tanh (except outputs).
__global__ void reduce_stage2(const float* __restrict__ p2,
                              const float* __restrict__ bias,
                              float* __restrict__ v,
                              float* __restrict__ out,
                              int write_out) {
    int i4 = 4 * (blockIdx.x * blockDim.x + threadIdx.x);
    if (i4 >= N_NEURONS) return;
    float4 acc = {0.f, 0.f, 0.f, 0.f};
#pragma unroll
    for (int g = 0; g < RG; ++g) {
        float4 p = *(const float4*)(p2 + (size_t)g * N_NEURONS + i4);
        acc.x += p.x; acc.y += p.y; acc.z += p.z; acc.w += p.w;
    }
    float av[4] = {acc.x, acc.y, acc.z, acc.w};
#pragma unroll
    for (int k = 0; k < 4; ++k) {
        int i = i4 + k;
        float val = av[k] + ((i >= INPUT_SIZE) ? bias[i - INPUT_SIZE] : 0.0f);
        float nv  = (i < N_NEURONS - OUTPUT_SIZE) ? tanhf(val) : val;
        v[i] = nv;
        if (write_out && i >= N_NEURONS - OUTPUT_SIZE)
            out[i - (N_NEURONS - OUTPUT_SIZE)] = val;
    }
}

// ---- fallback (small ws): multi-pass binned rescan path ----
__global__ void init_state_fb(const float* __restrict__ x, float* __restrict__ v) {
    int i = blockIdx.x * blockDim.x + threadIdx.x;
    if (i < N_NEURONS) v[i] = (i < INPUT_SIZE) ? x[i] : 0.0f;
}
__global__ void scatter_binned(const float* __restrict__ w,
                               const int*   __restrict__ src,
                               const int*   __restrict__ dst,
                               const float* __restrict__ v,
                               float*       __restrict__ partials,
                               int C) {
    __shared__ float bins[BIN];
    const int r = blockIdx.x / C;
    const int c = blockIdx.x % C;
    const int lo = r * BIN;
    const int hi = lo + BIN;
    for (int j = threadIdx.x; j < BIN; j += blockDim.x) bins[j] = 0.0f;
    __syncthreads();
    const int4*   src4 = (const int4*)src;
    const int4*   dst4 = (const int4*)dst;
    const float4* w4v  = (const float4*)w;
    const int stride = C * blockDim.x;
    for (int u = c * blockDim.x + threadIdx.x; u < VEC4; u += stride) {
        const int4   s4 = src4[u];
        const int4   d4 = dst4[u];
        const float4 wv = w4v[u];
        int   s[4] = {s4.x, s4.y, s4.z, s4.w};
        int   d[4] = {d4.x, d4.y, d4.z, d4.w};
        float ww[4] = {wv.x, wv.y, wv.z, wv.w};
#pragma unroll
        for (int k = 0; k < 4; ++k)
            if (d[k] >= lo && d[k] < hi)
                atomicAdd(&bins[d[k] - lo], v[s[k]] * ww[k]);
    }
    __syncthreads();
    float* o = partials + ((size_t)(r * C + c)) * BIN;
    for (int j = threadIdx.x; j < BIN; j += blockDim.x) o[j] = bins[j];
}
__global__ void reduce_update_fb(const float* __restrict__ partials,
                                 const float* __restrict__ bias,
                                 float* __restrict__ v,
                                 float* __restrict__ out,
                                 int C, int write_out) {
    int i4 = 4 * (blockIdx.x * blockDim.x + threadIdx.x);
    if (i4 >= N_NEURONS) return;
    const int r = i4 / BIN;
    const int j = i4 - r * BIN;
    const float* base = partials + ((size_t)r * C) * BIN + j;
    float4 acc = {0.f, 0.f, 0.f, 0.f};
    for (int c = 0; c < C; ++c) {
        float4 p = *(const float4*)(base + (size_t)c * BIN);
        acc.x += p.x; acc.y += p.y; acc.z += p.z; acc.w += p.w;
    }
    float av[4] = {acc.x, acc.y, acc.z, acc.w};
#pragma unroll
    for (int k = 0; k < 4; ++k) {
        int i = i4 + k;
        float val = av[k] + ((i >= INPUT_SIZE) ? bias[i - INPUT_SIZE] : 0.0f);
        float nv  = (i < N_NEURONS - OUTPUT_SIZE) ? tanhf(val) : val;
        v[i] = nv;
        if (write_out && i >= N_NEURONS - OUTPUT_SIZE)
            out[i - (N_NEURONS - OUTPUT_SIZE)] = val;
    }
}

extern "C" void kernel_launch(void* const* d_in, const int* in_sizes, int n_in,
                              void* d_out, int out_size, void* d_ws, size_t ws_size,
                              hipStream_t stream) {
    const float* x    = (const float*)d_in[0];
    const float* w    = (const float*)d_in[1];
    const float* bias = (const float*)d_in[2];
    const int*   src  = (const int*)d_in[3];
    const int*   dst  = (const int*)d_in[4];
    float* out = (float*)d_out;

    const int blk = 256;
    const int grid_n   = (N_NEURONS + blk - 1) / blk;
    const int red_grid = (N_NEURONS / 4 + blk - 1) / blk;

    // sorted-path ws layout: v | partials | p2 | recs | gcur
    float* v        = (float*)d_ws;
    float* partials = v + N_NEURONS;
    float* p2       = partials + (size_t)RANGES * CBLK * BIN;
    int2*  recs     = (int2*)(p2 + (size_t)RG * N_NEURONS);
    int*   gcur     = (int*)(recs + (size_t)RANGES * CAP);
    size_t need = (size_t)((char*)(gcur + RANGES) - (char*)d_ws);

    if (ws_size >= need) {
        init_all<<<grid_n, blk, 0, stream>>>(x, v, gcur);
        reorder_partition<<<B_CNT, RB_BLK, 0, stream>>>(w, src, dst, recs, gcur);
        for (int s = 0; s < STEPS; ++s) {
            scatter_sorted<<<RANGES * CBLK, SCAT_BLK, 0, stream>>>(
                recs, gcur, v, partials);
            reduce_stage1<<<dim3(red_grid, RG), blk, 0, stream>>>(partials, p2);
            reduce_stage2<<<red_grid, blk, 0, stream>>>(
                p2, bias, v, out, s == STEPS - 1 ? 1 : 0);
        }
    } else {
        long C = (long)(ws_size / 4 / N_NEURONS) - 1;
        if (C > 64) C = 64;
        if (C < 1) C = 1;
        float* part_fb = v + N_NEURONS;
        init_state_fb<<<grid_n, blk, 0, stream>>>(x, v);
        for (int s = 0; s < STEPS; ++s) {
            scatter_binned<<<RANGES * (int)C, SCAT_BLK, 0, stream>>>(
                w, src, dst, v, part_fb, (int)C);
            reduce_update_fb<<<red_grid, blk, 0, stream>>>(
                part_fb, bias, v, out, (int)C, s == STEPS - 1 ? 1 : 0);
        }
    }
}